// Round 1
// baseline (1026.109 us; speedup 1.0000x reference)
//
#include <hip/hip_runtime.h>
#include <stdint.h>

#define B_TOK 32768
#define IN    128
#define HID   128
#define NE    32
#define NC    128

typedef __attribute__((ext_vector_type(8))) __bf16 bf16x8;
typedef __attribute__((ext_vector_type(4))) float  f32x4;

static __device__ __forceinline__ unsigned short f2bf(float f) {
    union { float f; uint32_t u; } v; v.f = f;
    uint32_t u = v.u;
    return (unsigned short)((u + 0x7FFFu + ((u >> 16) & 1u)) >> 16);
}

// ---- prep: x fp32 -> bf16 --------------------------------------------------
__global__ void k_convert_x(const float* __restrict__ x, unsigned short* __restrict__ xb) {
    int i = (blockIdx.x * 256 + threadIdx.x) * 4;
    float4 v = *(const float4*)(x + i);
    ushort4 o;
    o.x = f2bf(v.x); o.y = f2bf(v.y); o.z = f2bf(v.z); o.w = f2bf(v.w);
    *(ushort4*)(xb + i) = o;
}

// ---- prep: W1T[e][h][i] = bf16(W1[e][i][h]) --------------------------------
__global__ void k_prep_w1t(const float* __restrict__ W1, unsigned short* __restrict__ W1T) {
    int idx = blockIdx.x * 256 + threadIdx.x;   // e*16384 + h*128 + i
    int i = idx & 127;
    int h = (idx >> 7) & 127;
    int e = idx >> 14;
    W1T[idx] = f2bf(W1[(e * 128 + i) * 128 + h]);
}

// ---- prep: W2cT[e][c][h] = bf16(sum_t W2[e][h][t]*Wc[t][c]); bc2 fold ------
__global__ void k_prep_w2c(const float* __restrict__ W2, const float* __restrict__ Wc,
                           const float* __restrict__ b2, const float* __restrict__ bc,
                           unsigned short* __restrict__ W2cT, float* __restrict__ bc2) {
    __shared__ float row[128];
    int e = blockIdx.x >> 7, h = blockIdx.x & 127;   // grid 32*128
    int c = threadIdx.x;                              // 128 threads
    row[c] = W2[(e * 128 + h) * 128 + c];
    __syncthreads();
    float acc = 0.f;
    #pragma unroll 8
    for (int t = 0; t < 128; ++t) acc += row[t] * Wc[t * 128 + c];   // row[t] broadcast, Wc coalesced
    W2cT[(e * 128 + c) * 128 + h] = f2bf(acc);
    if (h == 0) {
        float a2 = bc[c];
        for (int t = 0; t < 128; ++t) a2 += b2[e * 128 + t] * Wc[t * 128 + c];
        bc2[e * 128 + c] = a2;
    }
}

// ---- router: scores = softmax(relu(x @ Wg + bg), axis=1) -------------------
__global__ __launch_bounds__(256) void k_router(const float* __restrict__ x,
        const float* __restrict__ Wg, const float* __restrict__ bg,
        float* __restrict__ scores) {
    __shared__ float Wgs[128 * 32];
    __shared__ float xs[8][128];
    int tid = threadIdx.x;
    for (int j = tid; j < 4096; j += 256) Wgs[j] = Wg[j];
    int rb = blockIdx.x * 8;
    for (int j = tid; j < 8 * 128; j += 256)
        xs[j >> 7][j & 127] = x[(rb + (j >> 7)) * 128 + (j & 127)];
    __syncthreads();
    int r = tid >> 5;        // 0..7 row in tile
    int e = tid & 31;        // expert
    float acc = bg[e];
    #pragma unroll 8
    for (int i = 0; i < 128; ++i) acc += xs[r][i] * Wgs[i * 32 + e];
    acc = fmaxf(acc, 0.f);
    float m = acc;
    for (int off = 16; off > 0; off >>= 1) m = fmaxf(m, __shfl_xor(m, off, 32));
    float p = __expf(acc - m);
    float s = p;
    for (int off = 16; off > 0; off >>= 1) s += __shfl_xor(s, off, 32);
    scores[(size_t)(rb + r) * 32 + e] = p / s;
}

// ---- main fused: out[:,e,:] = relu(X@W1[e]+b1[e]) @ W2c[e] + bc2[e] --------
// block = 256 thr (4 waves), tile = 64 rows x expert e; wave handles 16 rows.
__global__ __launch_bounds__(256) void k_moe(const unsigned short* __restrict__ Xb,
        const unsigned short* __restrict__ W1T, const float* __restrict__ b1,
        const unsigned short* __restrict__ W2cT, const float* __restrict__ bc2,
        float* __restrict__ out) {
    __shared__ unsigned short Hs[64 * 136];   // pad 136: 2-way LDS conflicts max (free)
    const int e    = blockIdx.y;
    const int tid  = threadIdx.x;
    const int wave = tid >> 6;
    const int lane = tid & 63;
    const int l15  = lane & 15;
    const int quad = lane >> 4;
    const int row0 = blockIdx.x * 64 + wave * 16;

    // ---- GEMM1: H = relu(X @ W1 + b1), this wave's 16 rows x 128 cols
    bf16x8 a[4];
    const unsigned short* ap = Xb + (size_t)(row0 + l15) * 128 + quad * 8;
    a[0] = *(const bf16x8*)(ap);
    a[1] = *(const bf16x8*)(ap + 32);
    a[2] = *(const bf16x8*)(ap + 64);
    a[3] = *(const bf16x8*)(ap + 96);

    const unsigned short* w1p = W1T + e * (128 * 128) + l15 * 128 + quad * 8;
    const float* b1p = b1 + e * 128 + l15;

    #pragma unroll
    for (int nt = 0; nt < 8; ++nt) {
        float bias = b1p[nt * 16];
        f32x4 acc = { bias, bias, bias, bias };
        const unsigned short* bp = w1p + nt * 16 * 128;
        bf16x8 bf0 = *(const bf16x8*)(bp);
        bf16x8 bf1 = *(const bf16x8*)(bp + 32);
        bf16x8 bf2 = *(const bf16x8*)(bp + 64);
        bf16x8 bf3 = *(const bf16x8*)(bp + 96);
        acc = __builtin_amdgcn_mfma_f32_16x16x32_bf16(a[0], bf0, acc, 0, 0, 0);
        acc = __builtin_amdgcn_mfma_f32_16x16x32_bf16(a[1], bf1, acc, 0, 0, 0);
        acc = __builtin_amdgcn_mfma_f32_16x16x32_bf16(a[2], bf2, acc, 0, 0, 0);
        acc = __builtin_amdgcn_mfma_f32_16x16x32_bf16(a[3], bf3, acc, 0, 0, 0);
        // C/D: row = quad*4+r, col = nt*16+l15 -> relu, cvt, stash in A-layout source
        #pragma unroll
        for (int r = 0; r < 4; ++r) {
            float v = fmaxf(acc[r], 0.f);
            Hs[(wave * 16 + quad * 4 + r) * 136 + nt * 16 + l15] = f2bf(v);
        }
    }
    __syncthreads();

    // ---- GEMM2: OUT = H @ W2c + bc2
    bf16x8 ha[4];
    const unsigned short* hp = Hs + (wave * 16 + l15) * 136 + quad * 8;
    ha[0] = *(const bf16x8*)(hp);
    ha[1] = *(const bf16x8*)(hp + 32);
    ha[2] = *(const bf16x8*)(hp + 64);
    ha[3] = *(const bf16x8*)(hp + 96);

    const unsigned short* w2p = W2cT + e * (128 * 128) + l15 * 128 + quad * 8;
    const float* bcp = bc2 + e * 128 + l15;
    float* op = out + ((size_t)(row0 + quad * 4) * NE + e) * NC + l15;

    #pragma unroll
    for (int nt = 0; nt < 8; ++nt) {
        float bias = bcp[nt * 16];
        f32x4 acc = { bias, bias, bias, bias };
        const unsigned short* bp = w2p + nt * 16 * 128;
        bf16x8 bf0 = *(const bf16x8*)(bp);
        bf16x8 bf1 = *(const bf16x8*)(bp + 32);
        bf16x8 bf2 = *(const bf16x8*)(bp + 64);
        bf16x8 bf3 = *(const bf16x8*)(bp + 96);
        acc = __builtin_amdgcn_mfma_f32_16x16x32_bf16(ha[0], bf0, acc, 0, 0, 0);
        acc = __builtin_amdgcn_mfma_f32_16x16x32_bf16(ha[1], bf1, acc, 0, 0, 0);
        acc = __builtin_amdgcn_mfma_f32_16x16x32_bf16(ha[2], bf2, acc, 0, 0, 0);
        acc = __builtin_amdgcn_mfma_f32_16x16x32_bf16(ha[3], bf3, acc, 0, 0, 0);
        #pragma unroll
        for (int r = 0; r < 4; ++r) {
            // b = row0 + quad*4 + r, c = nt*16 + l15 ; 16 lanes -> 64B full sector
            op[(size_t)r * NE * NC + nt * 16] = acc[r];
        }
    }
}

extern "C" void kernel_launch(void* const* d_in, const int* in_sizes, int n_in,
                              void* d_out, int out_size, void* d_ws, size_t ws_size,
                              hipStream_t stream) {
    const float* x  = (const float*)d_in[0];
    const float* Wg = (const float*)d_in[1];
    const float* bg = (const float*)d_in[2];
    const float* W1 = (const float*)d_in[3];
    const float* b1 = (const float*)d_in[4];
    const float* W2 = (const float*)d_in[5];
    const float* b2 = (const float*)d_in[6];
    const float* Wc = (const float*)d_in[7];
    const float* bc = (const float*)d_in[8];

    float* out    = (float*)d_out;
    float* scores = out + (size_t)B_TOK * NE * NC;

    unsigned short* Xb   = (unsigned short*)d_ws;            // 32768*128 bf16 = 8 MB
    unsigned short* W1T  = Xb + (size_t)B_TOK * IN;          // 32*128*128 bf16 = 1 MB
    unsigned short* W2cT = W1T + NE * IN * HID;              // 32*128*128 bf16 = 1 MB
    float*          bc2  = (float*)(W2cT + NE * HID * NC);   // 32*128 f32 = 16 KB

    hipLaunchKernelGGL(k_convert_x, dim3((B_TOK * IN) / (256 * 4)), dim3(256), 0, stream, x, Xb);
    hipLaunchKernelGGL(k_prep_w1t,  dim3((NE * IN * HID) / 256),    dim3(256), 0, stream, W1, W1T);
    hipLaunchKernelGGL(k_prep_w2c,  dim3(NE * HID),                 dim3(128), 0, stream,
                       W2, Wc, b2, bc, W2cT, bc2);
    hipLaunchKernelGGL(k_router,    dim3(B_TOK / 8),                dim3(256), 0, stream,
                       x, Wg, bg, scores);
    hipLaunchKernelGGL(k_moe,       dim3(B_TOK / 64, NE),           dim3(256), 0, stream,
                       Xb, W1T, b1, W2cT, bc2, out);
}